// Round 1
// baseline (1450.572 us; speedup 1.0000x reference)
//
#include <hip/hip_runtime.h>
#include <math.h>

#define NNODES 1024
// node_agg: [node][k(16)][n(64)] = 1024*1024 floats
#define NODE_AGG_FLOATS (1024*1024)
#define CG_TOTAL 573

// ---------------- path tables ----------------
// order: 3 scal paths (l3=0), 5 V1 paths (l3=1), 5 V2 paths (l3=2)
__device__ __constant__ int PL1[13] = {0,1,2, 0,1,1,2,3, 0,1,2,2,3};
__device__ __constant__ int PL2[13] = {0,1,2, 1,0,2,1,2, 2,1,0,2,1};
__device__ __constant__ int PL3[13] = {0,0,0, 1,1,1,1,1, 2,2,2,2,2};
__device__ __constant__ int PCG[13] = {0,1,10, 35,44,53,98,143, 248,273,318,343,468};
__device__ __constant__ int AOFF[4] = {0,1,4,9};  // k-offset of l-block in 16-dim Y
__device__ __constant__ int BOFF[3] = {0,1,4};    // offset of l-block in 9-dim V

// ---------------- spherical-harmonic polynomial tables (for CG setup) ----------------
// flat lm index: l0:0, l1:1..3, l2:4..8, l3:9..15
__device__ __constant__ signed char SH_NT[16] = {1, 1,1,1, 1,1,2,1,2, 2,1,2,2,2,2,2};
__device__ __constant__ signed char SH_CID[16][2] = {
  {0,0},{1,0},{1,0},{1,0},
  {2,0},{2,0},{3,4},{2,0},{5,6},
  {7,8},{9,0},{10,11},{12,13},{10,11},{14,15},{16,17}};
__device__ __constant__ signed char SH_EXP[16][2][3] = {
  {{0,0,0},{0,0,0}},
  {{1,0,0},{0,0,0}}, {{0,1,0},{0,0,0}}, {{0,0,1},{0,0,0}},
  {{1,1,0},{0,0,0}}, {{0,1,1},{0,0,0}}, {{0,0,2},{0,0,0}}, {{1,0,1},{0,0,0}}, {{2,0,0},{0,2,0}},
  {{2,1,0},{0,3,0}}, {{1,1,1},{0,0,0}}, {{0,1,2},{0,1,0}}, {{0,0,3},{0,0,1}},
  {{1,0,2},{1,0,0}}, {{2,0,1},{0,2,1}}, {{3,0,0},{1,2,0}}};

__device__ double dfact_d(int n) { double r = 1.0; while (n > 1) { r *= n; n -= 2; } return r; }

// Computes the 13 CG tensors (573 floats) exactly as the reference does (float64 math).
__global__ void cg_setup(float* __restrict__ cg)
{
  int p = threadIdx.x;
  if (p >= 13) return;
  double S3 = sqrt(3.0), S5 = sqrt(5.0), S15 = sqrt(15.0);
  double C33 = sqrt(70.0)/4.0, C32 = sqrt(105.0)/2.0, C31 = sqrt(42.0)/4.0;
  double C30 = sqrt(7.0)/2.0,  CX  = sqrt(105.0);
  double CV[18] = {1.0, S3, S15, 1.5*S5, -0.5*S5, 0.5*S15, -0.5*S15,
                   3.0*C33, -C33, CX, 5.0*C31, -C31, 5.0*C30, -3.0*C30,
                   C32, -C32, C33, -3.0*C33};
  const int LOFF[4] = {0,1,4,9};
  int l1 = PL1[p], l2 = PL2[p], l3 = PL3[p];
  int n1 = 2*l1+1, n2 = 2*l2+1, n3 = 2*l3+1;
  double tmp[105];
  double ss = 0.0;
  int cnt = 0;
  for (int i = 0; i < n1; i++) {
    int lm1 = LOFF[l1] + i;
    for (int j = 0; j < n2; j++) {
      int lm2 = LOFF[l2] + j;
      for (int k = 0; k < n3; k++) {
        int lm3 = LOFF[l3] + k;
        double v = 0.0;
        for (int t1 = 0; t1 < SH_NT[lm1]; t1++)
        for (int t2 = 0; t2 < SH_NT[lm2]; t2++)
        for (int t3 = 0; t3 < SH_NT[lm3]; t3++) {
          int a = SH_EXP[lm1][t1][0] + SH_EXP[lm2][t2][0] + SH_EXP[lm3][t3][0];
          int b = SH_EXP[lm1][t1][1] + SH_EXP[lm2][t2][1] + SH_EXP[lm3][t3][1];
          int c = SH_EXP[lm1][t1][2] + SH_EXP[lm2][t2][2] + SH_EXP[lm3][t3][2];
          if ((a & 1) | (b & 1) | (c & 1)) continue;
          // (integral of x^a y^b z^c over sphere) / (4*pi)
          double mi = dfact_d(a-1) * dfact_d(b-1) * dfact_d(c-1) / dfact_d(a+b+c+1);
          v += CV[SH_CID[lm1][t1]] * CV[SH_CID[lm2][t2]] * CV[SH_CID[lm3][t3]] * mi;
        }
        tmp[cnt] = v; ss += v*v; cnt++;
      }
    }
  }
  double scale = sqrt((double)(2*l3+1)) / sqrt(ss);
  float* dst = cg + PCG[p];
  for (int i = 0; i < cnt; i++) dst[i] = (float)(tmp[i] * scale);
}

__global__ void zero_ws(float4* __restrict__ p, int n4)
{
  int i = blockIdx.x * blockDim.x + threadIdx.x;
  if (i < n4) p[i] = make_float4(0.f, 0.f, 0.f, 0.f);
}

// ---------------- kernel 2: per-edge embed + scatter into node_agg ----------------
__global__ __launch_bounds__(256) void edge_embed(
    const float* __restrict__ vec, const float* __restrict__ x,
    const int* __restrict__ senders, const float* __restrict__ Ww,
    float* __restrict__ node_agg, int E)
{
  const int wid = threadIdx.x >> 6, lane = threadIdx.x & 63;
  const int e = blockIdx.x * 4 + wid;
  if (e >= E) return;

  const float S3 = 1.7320508075688772f, S5 = 2.23606797749979f, S15 = 3.872983346207417f;
  const float C33 = 2.091650066335189f, C32 = 5.123475382979799f, C31 = 1.6201851746019651f;
  const float C30 = 1.3228756555322954f, CX = 10.246950765959598f;

  float vx = vec[e*3+0], vy = vec[e*3+1], vz = vec[e*3+2];
  float d = sqrtf(vx*vx + vy*vy + vz*vz);
  float X = vx/d, Yv = vy/d, Z = vz/d;

  float Ya[16];
  Ya[0] = 1.f;
  Ya[1] = S3*X;  Ya[2] = S3*Yv;  Ya[3] = S3*Z;
  Ya[4] = S15*X*Yv; Ya[5] = S15*Yv*Z; Ya[6] = 0.5f*S5*(3.f*Z*Z - 1.f);
  Ya[7] = S15*X*Z;  Ya[8] = 0.5f*S15*(X*X - Yv*Yv);
  Ya[9]  = C33*Yv*(3.f*X*X - Yv*Yv);
  Ya[10] = CX*X*Yv*Z;
  Ya[11] = C31*Yv*(5.f*Z*Z - 1.f);
  Ya[12] = C30*Z*(5.f*Z*Z - 3.f);
  Ya[13] = C31*X*(5.f*Z*Z - 1.f);
  Ya[14] = C32*Z*(X*X - Yv*Yv);
  Ya[15] = C33*X*(X*X - 3.f*Yv*Yv);

  float xv = x[e*64 + lane];
  float w = 0.f;
  #pragma unroll
  for (int f = 0; f < 64; f++)
    w = fmaf(__shfl(xv, f), Ww[f*64 + lane], w);
  w *= 0.125f;  // / sqrt(64)

  const int s = senders[e];
  float* base = node_agg + s*1024 + lane;
  #pragma unroll
  for (int k = 0; k < 16; k++)
    atomicAdd(base + k*64, w * Ya[k]);
}

// ---------------- kernel 3: per-edge TP + MLP + output GEMMs ----------------
__global__ __launch_bounds__(256) void edge_main(
    const float* __restrict__ vec, const float* __restrict__ x,
    const float* __restrict__ V, const int* __restrict__ senders,
    const float* __restrict__ W1, const float* __restrict__ W2, const float* __restrict__ W3,
    const float* __restrict__ Wv1, const float* __restrict__ Wv2,
    const float* __restrict__ node_agg, const float* __restrict__ cg,
    float* __restrict__ out, int E, float inv_actc)
{
  __shared__ float Ash[1024];    // agg/4, layout [k(16)][n(64)]
  __shared__ float Vsh[576];     // V[e], layout [n(64)][9]
  __shared__ float CGs[573];
  __shared__ float V1sh[960];    // [m(320)][i(3)]
  __shared__ float V2sh[1600];   // [m(320)][i(5)]
  __shared__ float hbuf[256];    // [x(64) | scal(192: n*3+p)]
  __shared__ float h1[64];
  __shared__ float h2[64];

  const int e = blockIdx.x;
  const int t = threadIdx.x;
  const int s = senders[e];

  for (int i = t; i < 1024; i += 256) Ash[i] = node_agg[s*1024 + i] * 0.25f;  // / sqrt(16)
  for (int i = t; i < 576; i += 256)  Vsh[i] = V[e*576 + i];
  for (int i = t; i < 573; i += 256)  CGs[i] = cg[i];
  if (t < 64) hbuf[t] = x[e*64 + t];
  __syncthreads();

  // ---- tensor products: 13 paths x 64 channels ----
  for (int idx = t; idx < 13*64; idx += 256) {
    int p = idx >> 6, n = idx & 63;
    int l1 = PL1[p], l2 = PL2[p], l3 = PL3[p];
    int n1 = 2*l1+1, n2 = 2*l2+1, n3 = 2*l3+1;
    const float* C = &CGs[PCG[p]];
    const float* Arow = &Ash[AOFF[l1]*64 + n];  // A_i at Arow[i*64]
    const float* Brow = &Vsh[n*9 + BOFF[l2]];
    float ok[5] = {0.f,0.f,0.f,0.f,0.f};
    int ci = 0;
    for (int i = 0; i < n1; i++) {
      float a = Arow[i*64];
      for (int j = 0; j < n2; j++) {
        float ab = a * Brow[j];
        for (int k = 0; k < n3; k++)
          ok[k] = fmaf(ab, C[ci++], ok[k]);
      }
    }
    if (l3 == 0) {
      hbuf[64 + n*3 + p] = ok[0];
    } else if (l3 == 1) {
      int pb = p - 3;
      for (int k = 0; k < 3; k++) V1sh[(pb*64 + n)*3 + k] = ok[k];
    } else {
      int pb = p - 8;
      for (int k = 0; k < 5; k++) V2sh[(pb*64 + n)*5 + k] = ok[k];
    }
  }
  __syncthreads();

  // ---- MLP ----
  if (t < 64) {
    float acc = 0.f;
    for (int i = 0; i < 256; i++) acc = fmaf(hbuf[i], W1[i*64 + t], acc);
    acc *= (1.f/16.f);
    h1[t] = acc / (1.f + expf(-acc)) * inv_actc;
  }
  __syncthreads();
  if (t < 64) {
    float acc = 0.f;
    for (int i = 0; i < 64; i++) acc = fmaf(h1[i], W2[i*64 + t], acc);
    acc *= 0.125f;
    h2[t] = acc / (1.f + expf(-acc)) * inv_actc;
  }
  __syncthreads();
  if (t < 64) {
    float acc = 0.f;
    for (int i = 0; i < 64; i++) acc = fmaf(h2[i], W3[i*64 + t], acc);
    acc *= 0.125f;
    float vx = vec[e*3+0], vy = vec[e*3+1], vz = vec[e*3+2];
    float d = sqrtf(vx*vx + vy*vy + vz*vz);
    float u = 0.f;
    if (d < 1.f) {
      float d2 = d*d, d3 = d2*d, d6 = d3*d3, d7 = d6*d, d8 = d7*d;
      u = 1.f - 28.f*d6 + 48.f*d7 - 21.f*d8;
    }
    out[e*64 + t] = u * acc;
  }

  // ---- output contractions ----
  float* vout = out + (size_t)E*64 + (size_t)e*576;
  const float s320 = 0.05590169943749474f;  // 1/sqrt(320)
  if (t < 192) {
    int i = t >> 6, o = t & 63;
    float acc = 0.f;
    for (int m = 0; m < 320; m++) acc = fmaf(V1sh[m*3 + i], Wv1[m*64 + o], acc);
    vout[o*9 + 1 + i] = acc * s320;
  }
  for (int idx = t; idx < 320; idx += 256) {
    int i = idx >> 6, o = idx & 63;
    float acc = 0.f;
    for (int m = 0; m < 320; m++) acc = fmaf(V2sh[m*5 + i], Wv2[m*64 + o], acc);
    vout[o*9 + 4 + i] = acc * s320;
  }
  if (t < 64) vout[t*9] = 0.f;
}

extern "C" void kernel_launch(void* const* d_in, const int* in_sizes, int n_in,
                              void* d_out, int out_size, void* d_ws, size_t ws_size,
                              hipStream_t stream)
{
  const float* vec     = (const float*)d_in[0];
  const float* x       = (const float*)d_in[1];
  const float* V       = (const float*)d_in[2];
  const int*   senders = (const int*)  d_in[3];
  const float* Ww      = (const float*)d_in[4];
  const float* W1      = (const float*)d_in[5];
  const float* W2      = (const float*)d_in[6];
  const float* W3      = (const float*)d_in[7];
  const float* Wv1     = (const float*)d_in[8];
  const float* Wv2     = (const float*)d_in[9];
  float* out = (float*)d_out;
  const int E = in_sizes[0] / 3;

  float* node_agg = (float*)d_ws;
  float* cg = node_agg + NODE_AGG_FLOATS;

  // ACT_C: exact replica of the reference's Riemann sum (host, double).
  double ssum = 0.0;
  const double dz = 24.0 / 200000.0;
  for (int i = 0; i <= 200000; i++) {
    double z = -12.0 + dz * i;
    double ph = exp(-0.5 * z * z) * 0.3989422804014327;
    double sl = z / (1.0 + exp(-z));
    ssum += sl * sl * ph;
  }
  const float inv_actc = (float)(1.0 / sqrt(ssum * dz));

  zero_ws<<<(NODE_AGG_FLOATS/4 + 255)/256, 256, 0, stream>>>((float4*)node_agg, NODE_AGG_FLOATS/4);
  cg_setup<<<1, 64, 0, stream>>>(cg);
  edge_embed<<<(E + 3)/4, 256, 0, stream>>>(vec, x, senders, Ww, node_agg, E);
  edge_main<<<E, 256, 0, stream>>>(vec, x, V, senders, W1, W2, W3, Wv1, Wv2,
                                   node_agg, cg, out, E, inv_actc);
}

// Round 3
// 402.204 us; speedup vs baseline: 3.6066x; 3.6066x over previous
//
#include <hip/hip_runtime.h>
#include <math.h>

#define NNODES 1024
#define EDGES 16384
#define EB 8   // edges per block in edge_main

typedef __attribute__((ext_vector_type(8))) short short8;
typedef __attribute__((ext_vector_type(4))) float f32x4;

__device__ __forceinline__ unsigned short f2bf(float f) {
  union { float f; unsigned int u; } v; v.f = f;
  unsigned int r = v.u + 0x7fffu + ((v.u >> 16) & 1u);
  return (unsigned short)(r >> 16);
}

// ---------------- path tables ----------------
__device__ __constant__ int PL1[13] = {0,1,2, 0,1,1,2,3, 0,1,2,2,3};
__device__ __constant__ int PL2[13] = {0,1,2, 1,0,2,1,2, 2,1,0,2,1};
__device__ __constant__ int PL3[13] = {0,0,0, 1,1,1,1,1, 2,2,2,2,2};
__device__ __constant__ int PCG[13] = {0,1,10, 35,44,53,98,143, 248,273,318,343,468};

// ---------------- SH polynomial tables for CG setup ----------------
__device__ __constant__ signed char SH_NT[16] = {1, 1,1,1, 1,1,2,1,2, 2,1,2,2,2,2,2};
__device__ __constant__ signed char SH_CID[16][2] = {
  {0,0},{1,0},{1,0},{1,0},
  {2,0},{2,0},{3,4},{2,0},{5,6},
  {7,8},{9,0},{10,11},{12,13},{10,11},{14,15},{16,17}};
__device__ __constant__ signed char SH_EXP[16][2][3] = {
  {{0,0,0},{0,0,0}},
  {{1,0,0},{0,0,0}}, {{0,1,0},{0,0,0}}, {{0,0,1},{0,0,0}},
  {{1,1,0},{0,0,0}}, {{0,1,1},{0,0,0}}, {{0,0,2},{0,0,0}}, {{1,0,1},{0,0,0}}, {{2,0,0},{0,2,0}},
  {{2,1,0},{0,3,0}}, {{1,1,1},{0,0,0}}, {{0,1,2},{0,1,0}}, {{0,0,3},{0,0,1}},
  {{1,0,2},{1,0,0}}, {{2,0,1},{0,2,1}}, {{3,0,0},{1,2,0}}};

__device__ double dfact_d(int n) { double r = 1.0; while (n > 1) { r *= n; n -= 2; } return r; }

// 13 blocks (one per path) x 128 threads (one per CG entry)
__global__ void cg_setup(float* __restrict__ cg)
{
  __shared__ double sh[128];
  const int p = blockIdx.x;
  const int t = threadIdx.x;
  double S3 = sqrt(3.0), S5 = sqrt(5.0), S15 = sqrt(15.0);
  double C33 = sqrt(70.0)/4.0, C32 = sqrt(105.0)/2.0, C31 = sqrt(42.0)/4.0;
  double C30 = sqrt(7.0)/2.0,  CX  = sqrt(105.0);
  double CV[18] = {1.0, S3, S15, 1.5*S5, -0.5*S5, 0.5*S15, -0.5*S15,
                   3.0*C33, -C33, CX, 5.0*C31, -C31, 5.0*C30, -3.0*C30,
                   C32, -C32, C33, -3.0*C33};
  const int LOFF[4] = {0,1,4,9};
  int l1 = PL1[p], l2 = PL2[p], l3 = PL3[p];
  int n1 = 2*l1+1, n2 = 2*l2+1, n3 = 2*l3+1;
  int nent = n1*n2*n3;
  double v = 0.0;
  if (t < nent) {
    int i = t / (n2*n3);
    int rem = t - i*(n2*n3);
    int j = rem / n3;
    int k = rem - j*n3;
    int lm1 = LOFF[l1]+i, lm2 = LOFF[l2]+j, lm3 = LOFF[l3]+k;
    for (int t1 = 0; t1 < SH_NT[lm1]; t1++)
    for (int t2 = 0; t2 < SH_NT[lm2]; t2++)
    for (int t3 = 0; t3 < SH_NT[lm3]; t3++) {
      int a = SH_EXP[lm1][t1][0] + SH_EXP[lm2][t2][0] + SH_EXP[lm3][t3][0];
      int b = SH_EXP[lm1][t1][1] + SH_EXP[lm2][t2][1] + SH_EXP[lm3][t3][1];
      int c = SH_EXP[lm1][t1][2] + SH_EXP[lm2][t2][2] + SH_EXP[lm3][t3][2];
      if ((a & 1) | (b & 1) | (c & 1)) continue;
      double mi = dfact_d(a-1) * dfact_d(b-1) * dfact_d(c-1) / dfact_d(a+b+c+1);
      v += CV[SH_CID[lm1][t1]] * CV[SH_CID[lm2][t2]] * CV[SH_CID[lm3][t3]] * mi;
    }
  }
  sh[t] = (t < nent) ? v*v : 0.0;
  __syncthreads();
  for (int d = 64; d > 0; d >>= 1) {
    if (t < d) sh[t] += sh[t+d];
    __syncthreads();
  }
  double scale = sqrt((double)(2*l3+1)) / sqrt(sh[0]);
  if (t < nent) cg[PCG[p] + t] = (float)(v * scale);
}

// ---------------- ACT_C: device-side replica of the reference Riemann sum ----------------
__global__ void act_setup(float* __restrict__ dst)
{
  __shared__ double sh[256];
  const int t = threadIdx.x;
  const double dz = 24.0 / 200000.0;
  double s = 0.0;
  for (int i = t; i <= 200000; i += 256) {
    double z = -12.0 + dz * i;
    double ph = exp(-0.5 * z * z) * 0.3989422804014327;
    double sl = z / (1.0 + exp(-z));
    s += sl * sl * ph;
  }
  sh[t] = s;
  __syncthreads();
  for (int d = 128; d > 0; d >>= 1) {
    if (t < d) sh[t] += sh[t + d];
    __syncthreads();
  }
  if (t == 0) dst[0] = (float)(1.0 / sqrt(sh[0] * dz));
}

// ---------------- weight fragment pre-pack: [K][64] f32 -> bf16 B-fragments ----------------
// frag f = ntile*nk + ks; element j of lane l = W[ks*32 + (l>>4)*8 + j][ntile*16 + (l&15)]
__global__ void conv_w(const float* __restrict__ src, unsigned short* __restrict__ dst, int nk)
{
  int f = blockIdx.x;
  int nt = f / nk;
  int ks = f - nt*nk;
  int lane = threadIdx.x;
  unsigned short us[8];
  #pragma unroll
  for (int j = 0; j < 8; j++) {
    float v = src[(ks*32 + (lane>>4)*8 + j)*64 + nt*16 + (lane & 15)];
    us[j] = f2bf(v);
  }
  uint4 pk;
  pk.x = (unsigned)us[0] | ((unsigned)us[1] << 16);
  pk.y = (unsigned)us[2] | ((unsigned)us[3] << 16);
  pk.z = (unsigned)us[4] | ((unsigned)us[5] << 16);
  pk.w = (unsigned)us[6] | ((unsigned)us[7] << 16);
  *(uint4*)(dst + ((size_t)f*64 + lane)*8) = pk;
}

// ---------------- graph bucketing ----------------
__global__ void k_zero(int* __restrict__ counts) { counts[threadIdx.x] = 0; }

__global__ void k_hist(const int* __restrict__ senders, int* __restrict__ counts) {
  int i = blockIdx.x * blockDim.x + threadIdx.x;
  if (i < EDGES) atomicAdd(&counts[senders[i]], 1);
}

__global__ void k_scan(const int* __restrict__ counts, int* __restrict__ offsets, int* __restrict__ cursor) {
  __shared__ int sh[1024];
  int t = threadIdx.x;
  int c = counts[t];
  sh[t] = c; __syncthreads();
  for (int d = 1; d < 1024; d <<= 1) {
    int v = (t >= d) ? sh[t-d] : 0;
    __syncthreads();
    sh[t] += v;
    __syncthreads();
  }
  int incl = sh[t];
  int excl = incl - c;
  offsets[t] = excl;
  cursor[t] = excl;
  if (t == 1023) offsets[1024] = incl;
}

__global__ void k_scatter(const int* __restrict__ senders, int* __restrict__ cursor, int* __restrict__ elist) {
  int i = blockIdx.x * blockDim.x + threadIdx.x;
  if (i < EDGES) {
    int pos = atomicAdd(&cursor[senders[i]], 1);
    elist[pos] = i;
  }
}

// ---------------- w = x @ W_w / 8 ----------------
__global__ __launch_bounds__(256) void k_edge_w(
    const float* __restrict__ x, const float* __restrict__ Ww,
    float* __restrict__ w_ws, int E)
{
  const int wid = threadIdx.x >> 6, lane = threadIdx.x & 63;
  const int e = blockIdx.x * 4 + wid;
  if (e >= E) return;
  float xv = x[e*64 + lane];
  float w = 0.f;
  #pragma unroll
  for (int f = 0; f < 64; f++)
    w = fmaf(__shfl(xv, f), Ww[f*64 + lane], w);
  w_ws[e*64 + lane] = w * 0.125f;
}

// ---------------- node aggregation (one wave per node) ----------------
__global__ __launch_bounds__(256) void k_node(
    const float* __restrict__ vec, const float* __restrict__ w_ws,
    const int* __restrict__ offsets, const int* __restrict__ elist,
    float* __restrict__ node_agg)
{
  const int wid = threadIdx.x >> 6, lane = threadIdx.x & 63;
  const int s = blockIdx.x * 4 + wid;
  const int beg = offsets[s], end = offsets[s+1];

  const float S3 = 1.7320508075688772f, S5 = 2.23606797749979f, S15 = 3.872983346207417f;
  const float C33 = 2.091650066335189f, C32 = 5.123475382979799f, C31 = 1.6201851746019651f;
  const float C30 = 1.3228756555322954f, CX = 10.246950765959598f;

  float A[16];
  #pragma unroll
  for (int k = 0; k < 16; k++) A[k] = 0.f;

  for (int ii = beg; ii < end; ii++) {
    int e = elist[ii];
    float vx = vec[e*3+0], vy = vec[e*3+1], vz = vec[e*3+2];
    float d = sqrtf(vx*vx + vy*vy + vz*vz);
    float X = vx/d, Yv = vy/d, Z = vz/d;
    float y[16];
    y[0] = 1.f;
    y[1] = S3*X;  y[2] = S3*Yv;  y[3] = S3*Z;
    y[4] = S15*X*Yv; y[5] = S15*Yv*Z; y[6] = 0.5f*S5*(3.f*Z*Z - 1.f);
    y[7] = S15*X*Z;  y[8] = 0.5f*S15*(X*X - Yv*Yv);
    y[9]  = C33*Yv*(3.f*X*X - Yv*Yv);
    y[10] = CX*X*Yv*Z;
    y[11] = C31*Yv*(5.f*Z*Z - 1.f);
    y[12] = C30*Z*(5.f*Z*Z - 3.f);
    y[13] = C31*X*(5.f*Z*Z - 1.f);
    y[14] = C32*Z*(X*X - Yv*Yv);
    y[15] = C33*X*(X*X - 3.f*Yv*Yv);
    float wv = w_ws[e*64 + lane];
    #pragma unroll
    for (int k = 0; k < 16; k++) A[k] = fmaf(wv, y[k], A[k]);
  }
  float* dst = node_agg + s*1024 + lane;
  #pragma unroll
  for (int k = 0; k < 16; k++) dst[k*64] = A[k];
}

// ---------------- TP helper (fully unrolled; cg reads are wave-uniform -> s_load) ----------------
template<int L1, int L2, int L3>
__device__ __forceinline__ void tp_path(const float* __restrict__ cgp,
    const float a[16], const float b[9], float o[2*L3+1])
{
  constexpr int N1 = 2*L1+1, N2 = 2*L2+1, N3 = 2*L3+1;
  constexpr int AO = (L1==0) ? 0 : (L1==1) ? 1 : (L1==2) ? 4 : 9;
  constexpr int BO = (L2==0) ? 0 : (L2==1) ? 1 : 4;
  #pragma unroll
  for (int k = 0; k < N3; k++) o[k] = 0.f;
  int ci = 0;
  #pragma unroll
  for (int i = 0; i < N1; i++) {
    #pragma unroll
    for (int j = 0; j < N2; j++) {
      float ab = a[AO+i] * b[BO+j];
      #pragma unroll
      for (int k = 0; k < N3; k++) { o[k] = fmaf(ab, cgp[ci], o[k]); ci++; }
    }
  }
}

// ---------------- main fused kernel: TP -> MFMA GEMMs -> outputs ----------------
__global__ __launch_bounds__(256, 2) void edge_main(
    const float* __restrict__ vec, const float* __restrict__ x,
    const float* __restrict__ V, const int* __restrict__ senders,
    const float* __restrict__ node_agg, const float* __restrict__ cg,
    const unsigned short* __restrict__ wv1f, const unsigned short* __restrict__ wv2f,
    const unsigned short* __restrict__ w1f, const unsigned short* __restrict__ w2f,
    const unsigned short* __restrict__ w3f,
    float* __restrict__ out, int E, const float* __restrict__ actc)
{
  // row stride 328 bf16 = 656B = 164 words = 4 mod 32 banks (2-way = free)
  __shared__ __align__(16) unsigned short V1sh[24*328];  // rows (eloc*3+i), K=320
  __shared__ __align__(16) unsigned short V2sh[40*328];  // rows (eloc*5+i), K=320
  __shared__ __align__(16) unsigned short zrow[336];     // shared zero row for M-tile padding
  __shared__ __align__(16) unsigned short hsh[8*264];    // rows=edges, K=256 = [x(64)|scal(192)]
  __shared__ __align__(16) unsigned short h1sh[8*72];
  __shared__ __align__(16) unsigned short h2sh[8*72];
  __shared__ __align__(16) float vtmp[4][576];
  __shared__ float ush[EB];

  const int t = threadIdx.x;
  const int wid = t >> 6, lane = t & 63;
  const int e0 = blockIdx.x * EB;
  const size_t E64 = (size_t)E * 64;
  const float inv_actc = *actc;

  if (t < 168) ((unsigned int*)zrow)[t] = 0u;

  // x -> hsh[:, 0:64]
  #pragma unroll
  for (int it = 0; it < 2; it++) {
    int idx = t + it*256;
    int el = idx >> 6, o = idx & 63;
    hsh[el*264 + o] = f2bf(x[(e0+el)*64 + o]);
  }

  // ---- TP phase: each wave handles 2 edges ----
  #pragma clang loop unroll(disable)
  for (int rep = 0; rep < 2; rep++) {
    const int eloc = wid*2 + rep;
    const int eg = e0 + eloc;
    const int s = senders[eg];

    float a[16];
    const float* nap = node_agg + s*1024 + lane;
    #pragma unroll
    for (int k = 0; k < 16; k++) a[k] = nap[k*64] * 0.25f;

    const float* vp = V + (size_t)eg*576;
    #pragma unroll
    for (int i = 0; i < 9; i++) vtmp[wid][i*64 + lane] = vp[i*64 + lane];
    float b[9];
    #pragma unroll
    for (int j = 0; j < 9; j++) b[j] = vtmp[wid][lane*9 + j];

    float o1[1], o3[3], o5[5];
    // scal paths -> hsh cols 64 + lane*3 + p
    tp_path<0,0,0>(cg + 0,  a, b, o1); hsh[eloc*264 + 64 + lane*3 + 0] = f2bf(o1[0]);
    tp_path<1,1,0>(cg + 1,  a, b, o1); hsh[eloc*264 + 64 + lane*3 + 1] = f2bf(o1[0]);
    tp_path<2,2,0>(cg + 10, a, b, o1); hsh[eloc*264 + 64 + lane*3 + 2] = f2bf(o1[0]);
    // V1 paths (K index = pb*64 + lane)
    tp_path<0,1,1>(cg + 35, a, b, o3);
    { int r = eloc*3; for (int i=0;i<3;i++) V1sh[(r+i)*328 + 0*64 + lane] = f2bf(o3[i]); }
    tp_path<1,0,1>(cg + 44, a, b, o3);
    { int r = eloc*3; for (int i=0;i<3;i++) V1sh[(r+i)*328 + 1*64 + lane] = f2bf(o3[i]); }
    tp_path<1,2,1>(cg + 53, a, b, o3);
    { int r = eloc*3; for (int i=0;i<3;i++) V1sh[(r+i)*328 + 2*64 + lane] = f2bf(o3[i]); }
    tp_path<2,1,1>(cg + 98, a, b, o3);
    { int r = eloc*3; for (int i=0;i<3;i++) V1sh[(r+i)*328 + 3*64 + lane] = f2bf(o3[i]); }
    tp_path<3,2,1>(cg + 143, a, b, o3);
    { int r = eloc*3; for (int i=0;i<3;i++) V1sh[(r+i)*328 + 4*64 + lane] = f2bf(o3[i]); }
    // V2 paths
    tp_path<0,2,2>(cg + 248, a, b, o5);
    { int r = eloc*5; for (int i=0;i<5;i++) V2sh[(r+i)*328 + 0*64 + lane] = f2bf(o5[i]); }
    tp_path<1,1,2>(cg + 273, a, b, o5);
    { int r = eloc*5; for (int i=0;i<5;i++) V2sh[(r+i)*328 + 1*64 + lane] = f2bf(o5[i]); }
    tp_path<2,0,2>(cg + 318, a, b, o5);
    { int r = eloc*5; for (int i=0;i<5;i++) V2sh[(r+i)*328 + 2*64 + lane] = f2bf(o5[i]); }
    tp_path<2,2,2>(cg + 343, a, b, o5);
    { int r = eloc*5; for (int i=0;i<5;i++) V2sh[(r+i)*328 + 3*64 + lane] = f2bf(o5[i]); }
    tp_path<3,1,2>(cg + 468, a, b, o5);
    { int r = eloc*5; for (int i=0;i<5;i++) V2sh[(r+i)*328 + 4*64 + lane] = f2bf(o5[i]); }

    if (lane == 0) {
      float vx = vec[eg*3+0], vy = vec[eg*3+1], vz = vec[eg*3+2];
      float d = sqrtf(vx*vx + vy*vy + vz*vz);
      float u = 0.f;
      if (d < 1.f) {
        float d3 = d*d*d, d6 = d3*d3, d7 = d6*d, d8 = d7*d;
        u = 1.f - 28.f*d6 + 48.f*d7 - 21.f*d8;
      }
      ush[eloc] = u;
    }
  }
  __syncthreads();

  // ---- MFMA GEMM phase: wave wid owns output-column tile ntile=wid (16 cols) ----
  const int ntile = wid;
  const int qr = lane >> 4;
  const int ml = lane & 15;
  const float s320 = 0.05590169943749474f;  // 1/sqrt(320)

  // V1: M=24 (2 tiles), K=320
  {
    f32x4 acc[2]; acc[0] = (f32x4){0,0,0,0}; acc[1] = (f32x4){0,0,0,0};
    const unsigned short* p0 = &V1sh[ml*328];
    const unsigned short* p1 = (16+ml < 24) ? &V1sh[(16+ml)*328] : zrow;
    const unsigned short* bb = wv1f + ((size_t)(ntile*10)*64 + lane)*8;
    #pragma unroll
    for (int ks = 0; ks < 10; ks++) {
      short8 bf = *(const short8*)(bb + ks*512);
      int ao = ks*32 + qr*8;
      short8 af0 = *(const short8*)(p0 + ao);
      short8 af1 = *(const short8*)(p1 + ao);
      acc[0] = __builtin_amdgcn_mfma_f32_16x16x32_bf16(af0, bf, acc[0], 0, 0, 0);
      acc[1] = __builtin_amdgcn_mfma_f32_16x16x32_bf16(af1, bf, acc[1], 0, 0, 0);
    }
    #pragma unroll
    for (int mt = 0; mt < 2; mt++) {
      #pragma unroll
      for (int r = 0; r < 4; r++) {
        int row = mt*16 + qr*4 + r;
        if (row < 24) {
          int el = row / 3, i = row - (row/3)*3;
          out[E64 + (size_t)(e0+el)*576 + (ntile*16+ml)*9 + 1 + i] = acc[mt][r] * s320;
        }
      }
    }
  }

  // V2: M=40 (3 tiles), K=320
  {
    f32x4 acc[3]; acc[0] = (f32x4){0,0,0,0}; acc[1] = (f32x4){0,0,0,0}; acc[2] = (f32x4){0,0,0,0};
    const unsigned short* p0 = &V2sh[ml*328];
    const unsigned short* p1 = &V2sh[(16+ml)*328];
    const unsigned short* p2 = (32+ml < 40) ? &V2sh[(32+ml)*328] : zrow;
    const unsigned short* bb = wv2f + ((size_t)(ntile*10)*64 + lane)*8;
    #pragma unroll
    for (int ks = 0; ks < 10; ks++) {
      short8 bf = *(const short8*)(bb + ks*512);
      int ao = ks*32 + qr*8;
      short8 af0 = *(const short8*)(p0 + ao);
      short8 af1 = *(const short8*)(p1 + ao);
      short8 af2 = *(const short8*)(p2 + ao);
      acc[0] = __builtin_amdgcn_mfma_f32_16x16x32_bf16(af0, bf, acc[0], 0, 0, 0);
      acc[1] = __builtin_amdgcn_mfma_f32_16x16x32_bf16(af1, bf, acc[1], 0, 0, 0);
      acc[2] = __builtin_amdgcn_mfma_f32_16x16x32_bf16(af2, bf, acc[2], 0, 0, 0);
    }
    #pragma unroll
    for (int mt = 0; mt < 3; mt++) {
      #pragma unroll
      for (int r = 0; r < 4; r++) {
        int row = mt*16 + qr*4 + r;
        if (row < 40) {
          int el = row / 5, i = row - (row/5)*5;
          out[E64 + (size_t)(e0+el)*576 + (ntile*16+ml)*9 + 4 + i] = acc[mt][r] * s320;
        }
      }
    }
  }

  // V_out channel 0 = 0
  #pragma unroll
  for (int it = 0; it < 2; it++) {
    int idx = t + it*256;
    int el = idx >> 6, o = idx & 63;
    out[E64 + (size_t)(e0+el)*576 + o*9] = 0.f;
  }

  // ---- MLP via MFMA (M=8 real rows padded to 16) ----
  const unsigned short* hp = (ml < 8) ? &hsh[ml*264] : zrow;
  {
    f32x4 c = (f32x4){0,0,0,0};
    const unsigned short* bb = w1f + ((size_t)(ntile*8)*64 + lane)*8;
    #pragma unroll
    for (int ks = 0; ks < 8; ks++) {
      short8 bf = *(const short8*)(bb + ks*512);
      short8 af = *(const short8*)(hp + ks*32 + qr*8);
      c = __builtin_amdgcn_mfma_f32_16x16x32_bf16(af, bf, c, 0, 0, 0);
    }
    #pragma unroll
    for (int r = 0; r < 4; r++) {
      int row = qr*4 + r;
      if (row < 8) {
        float v = c[r] * 0.0625f;
        float sv = v / (1.f + expf(-v)) * inv_actc;
        h1sh[row*72 + ntile*16 + ml] = f2bf(sv);
      }
    }
  }
  __syncthreads();
  {
    f32x4 c = (f32x4){0,0,0,0};
    const unsigned short* ap = (ml < 8) ? &h1sh[ml*72] : zrow;
    const unsigned short* bb = w2f + ((size_t)(ntile*2)*64 + lane)*8;
    #pragma unroll
    for (int ks = 0; ks < 2; ks++) {
      short8 bf = *(const short8*)(bb + ks*512);
      short8 af = *(const short8*)(ap + ks*32 + qr*8);
      c = __builtin_amdgcn_mfma_f32_16x16x32_bf16(af, bf, c, 0, 0, 0);
    }
    #pragma unroll
    for (int r = 0; r < 4; r++) {
      int row = qr*4 + r;
      if (row < 8) {
        float v = c[r] * 0.125f;
        float sv = v / (1.f + expf(-v)) * inv_actc;
        h2sh[row*72 + ntile*16 + ml] = f2bf(sv);
      }
    }
  }
  __syncthreads();
  {
    f32x4 c = (f32x4){0,0,0,0};
    const unsigned short* ap = (ml < 8) ? &h2sh[ml*72] : zrow;
    const unsigned short* bb = w3f + ((size_t)(ntile*2)*64 + lane)*8;
    #pragma unroll
    for (int ks = 0; ks < 2; ks++) {
      short8 bf = *(const short8*)(bb + ks*512);
      short8 af = *(const short8*)(ap + ks*32 + qr*8);
      c = __builtin_amdgcn_mfma_f32_16x16x32_bf16(af, bf, c, 0, 0, 0);
    }
    #pragma unroll
    for (int r = 0; r < 4; r++) {
      int row = qr*4 + r;
      if (row < 8) {
        float v = c[r] * 0.125f;
        out[(size_t)(e0+row)*64 + ntile*16 + ml] = ush[row] * v;
      }
    }
  }
}

extern "C" void kernel_launch(void* const* d_in, const int* in_sizes, int n_in,
                              void* d_out, int out_size, void* d_ws, size_t ws_size,
                              hipStream_t stream)
{
  const float* vec     = (const float*)d_in[0];
  const float* x       = (const float*)d_in[1];
  const float* V       = (const float*)d_in[2];
  const int*   senders = (const int*)  d_in[3];
  const float* Ww      = (const float*)d_in[4];
  const float* W1      = (const float*)d_in[5];
  const float* W2      = (const float*)d_in[6];
  const float* W3      = (const float*)d_in[7];
  const float* Wv1     = (const float*)d_in[8];
  const float* Wv2     = (const float*)d_in[9];
  float* out = (float*)d_out;
  const int E = in_sizes[0] / 3;

  // ---- workspace layout (byte offsets, all 4KB-aligned) ----
  char* base = (char*)d_ws;
  float* node_agg = (float*)(base);                      // 4 MB
  float* w_ws     = (float*)(base + (4<<20));            // 4 MB
  float* cg       = (float*)(base + (8<<20));            // 573 floats
  float* actc     = (float*)(base + (8<<20) + 2400);     // 1 float
  int* counts     = (int*)  (base + (8<<20) + 4096);     // 4 KB
  int* offsets    = (int*)  (base + (8<<20) + 8192);     // 8 KB (1025 ints)
  int* cursor     = (int*)  (base + (8<<20) + 16384);    // 4 KB
  int* elist      = (int*)  (base + (8<<20) + 20480);    // 64 KB
  unsigned short* wv1f = (unsigned short*)(base + (8<<20) + 86016);   // 40 KB
  unsigned short* wv2f = (unsigned short*)(base + (8<<20) + 126976);  // 40 KB
  unsigned short* w1f  = (unsigned short*)(base + (8<<20) + 167936);  // 32 KB
  unsigned short* w2f  = (unsigned short*)(base + (8<<20) + 200704);  // 8 KB
  unsigned short* w3f  = (unsigned short*)(base + (8<<20) + 208896);  // 8 KB

  cg_setup<<<13, 128, 0, stream>>>(cg);
  act_setup<<<1, 256, 0, stream>>>(actc);
  conv_w<<<40, 64, 0, stream>>>(Wv1, wv1f, 10);
  conv_w<<<40, 64, 0, stream>>>(Wv2, wv2f, 10);
  conv_w<<<32, 64, 0, stream>>>(W1,  w1f,  8);
  conv_w<<<8,  64, 0, stream>>>(W2,  w2f,  2);
  conv_w<<<8,  64, 0, stream>>>(W3,  w3f,  2);
  k_zero<<<1, 1024, 0, stream>>>(counts);
  k_edge_w<<<(E+3)/4, 256, 0, stream>>>(x, Ww, w_ws, E);
  k_hist<<<E/256, 256, 0, stream>>>(senders, counts);
  k_scan<<<1, 1024, 0, stream>>>(counts, offsets, cursor);
  k_scatter<<<E/256, 256, 0, stream>>>(senders, cursor, elist);
  k_node<<<NNODES/4, 256, 0, stream>>>(vec, w_ws, offsets, elist, node_agg);
  edge_main<<<E/EB, 256, 0, stream>>>(vec, x, V, senders, node_agg, cg,
                                      wv1f, wv2f, w1f, w2f, w3f, out, E, actc);
}

// Round 4
// 205.249 us; speedup vs baseline: 7.0674x; 1.9596x over previous
//
#include <hip/hip_runtime.h>
#include <math.h>

#define NNODES 1024
#define EDGES 16384
#define EB 4   // edges per block in edge_main (one edge per wave)

typedef __attribute__((ext_vector_type(8))) short short8;
typedef __attribute__((ext_vector_type(4))) float f32x4;

__device__ __forceinline__ unsigned short f2bf(float f) {
  union { float f; unsigned int u; } v; v.f = f;
  unsigned int r = v.u + 0x7fffu + ((v.u >> 16) & 1u);
  return (unsigned short)(r >> 16);
}

// ---------------- path tables ----------------
__device__ __constant__ int PL1[13] = {0,1,2, 0,1,1,2,3, 0,1,2,2,3};
__device__ __constant__ int PL2[13] = {0,1,2, 1,0,2,1,2, 2,1,0,2,1};
__device__ __constant__ int PL3[13] = {0,0,0, 1,1,1,1,1, 2,2,2,2,2};
__device__ __constant__ int PCG[13] = {0,1,10, 35,44,53,98,143, 248,273,318,343,468};

// ---------------- SH polynomial tables for CG setup ----------------
__device__ __constant__ signed char SH_NT[16] = {1, 1,1,1, 1,1,2,1,2, 2,1,2,2,2,2,2};
__device__ __constant__ signed char SH_CID[16][2] = {
  {0,0},{1,0},{1,0},{1,0},
  {2,0},{2,0},{3,4},{2,0},{5,6},
  {7,8},{9,0},{10,11},{12,13},{10,11},{14,15},{16,17}};
__device__ __constant__ signed char SH_EXP[16][2][3] = {
  {{0,0,0},{0,0,0}},
  {{1,0,0},{0,0,0}}, {{0,1,0},{0,0,0}}, {{0,0,1},{0,0,0}},
  {{1,1,0},{0,0,0}}, {{0,1,1},{0,0,0}}, {{0,0,2},{0,0,0}}, {{1,0,1},{0,0,0}}, {{2,0,0},{0,2,0}},
  {{2,1,0},{0,3,0}}, {{1,1,1},{0,0,0}}, {{0,1,2},{0,1,0}}, {{0,0,3},{0,0,1}},
  {{1,0,2},{1,0,0}}, {{2,0,1},{0,2,1}}, {{3,0,0},{1,2,0}}};

__device__ double dfact_d(int n) { double r = 1.0; while (n > 1) { r *= n; n -= 2; } return r; }

// 13 blocks (one per path) x 128 threads (one per CG entry)
__global__ void cg_setup(float* __restrict__ cg)
{
  __shared__ double sh[128];
  const int p = blockIdx.x;
  const int t = threadIdx.x;
  double S3 = sqrt(3.0), S5 = sqrt(5.0), S15 = sqrt(15.0);
  double C33 = sqrt(70.0)/4.0, C32 = sqrt(105.0)/2.0, C31 = sqrt(42.0)/4.0;
  double C30 = sqrt(7.0)/2.0,  CX  = sqrt(105.0);
  double CV[18] = {1.0, S3, S15, 1.5*S5, -0.5*S5, 0.5*S15, -0.5*S15,
                   3.0*C33, -C33, CX, 5.0*C31, -C31, 5.0*C30, -3.0*C30,
                   C32, -C32, C33, -3.0*C33};
  const int LOFF[4] = {0,1,4,9};
  int l1 = PL1[p], l2 = PL2[p], l3 = PL3[p];
  int n1 = 2*l1+1, n2 = 2*l2+1, n3 = 2*l3+1;
  int nent = n1*n2*n3;
  double v = 0.0;
  if (t < nent) {
    int i = t / (n2*n3);
    int rem = t - i*(n2*n3);
    int j = rem / n3;
    int k = rem - j*n3;
    int lm1 = LOFF[l1]+i, lm2 = LOFF[l2]+j, lm3 = LOFF[l3]+k;
    for (int t1 = 0; t1 < SH_NT[lm1]; t1++)
    for (int t2 = 0; t2 < SH_NT[lm2]; t2++)
    for (int t3 = 0; t3 < SH_NT[lm3]; t3++) {
      int a = SH_EXP[lm1][t1][0] + SH_EXP[lm2][t2][0] + SH_EXP[lm3][t3][0];
      int b = SH_EXP[lm1][t1][1] + SH_EXP[lm2][t2][1] + SH_EXP[lm3][t3][1];
      int c = SH_EXP[lm1][t1][2] + SH_EXP[lm2][t2][2] + SH_EXP[lm3][t3][2];
      if ((a & 1) | (b & 1) | (c & 1)) continue;
      double mi = dfact_d(a-1) * dfact_d(b-1) * dfact_d(c-1) / dfact_d(a+b+c+1);
      v += CV[SH_CID[lm1][t1]] * CV[SH_CID[lm2][t2]] * CV[SH_CID[lm3][t3]] * mi;
    }
  }
  sh[t] = (t < nent) ? v*v : 0.0;
  __syncthreads();
  for (int d = 64; d > 0; d >>= 1) {
    if (t < d) sh[t] += sh[t+d];
    __syncthreads();
  }
  double scale = sqrt((double)(2*l3+1)) / sqrt(sh[0]);
  if (t < nent) cg[PCG[p] + t] = (float)(v * scale);
}

// ---------------- ACT_C stage 1: 128 partial sums (also zeroes hist counts) ----------------
__global__ void act1(double* __restrict__ partial, int* __restrict__ counts)
{
  __shared__ double sh[256];
  const int t = threadIdx.x;
  const int b = blockIdx.x;
  if (b < 4) counts[b*256 + t] = 0;
  const double dz = 24.0 / 200000.0;
  double s = 0.0;
  for (int i = b*256 + t; i <= 200000; i += 128*256) {
    double z = -12.0 + dz * i;
    double ph = exp(-0.5 * z * z) * 0.3989422804014327;
    double sl = z / (1.0 + exp(-z));
    s += sl * sl * ph;
  }
  sh[t] = s;
  __syncthreads();
  for (int d = 128; d > 0; d >>= 1) {
    if (t < d) sh[t] += sh[t + d];
    __syncthreads();
  }
  if (t == 0) partial[b] = sh[0];
}

// ---------------- ACT_C stage 2: final reduce ----------------
__global__ void act2(const double* __restrict__ partial, float* __restrict__ dst)
{
  __shared__ double sh[128];
  const int t = threadIdx.x;
  sh[t] = partial[t];
  __syncthreads();
  for (int d = 64; d > 0; d >>= 1) {
    if (t < d) sh[t] += sh[t + d];
    __syncthreads();
  }
  const double dz = 24.0 / 200000.0;
  if (t == 0) dst[0] = (float)(1.0 / sqrt(sh[0] * dz));
}

// ---------------- weight fragment pre-pack, all 5 weights in one launch ----------------
// frag f = ntile*nk + ks; element j of lane l = W[ks*32 + (l>>4)*8 + j][ntile*16 + (l&15)]
__global__ void conv_all(
    const float* __restrict__ Wv1, const float* __restrict__ Wv2,
    const float* __restrict__ W1, const float* __restrict__ W2, const float* __restrict__ W3,
    unsigned short* __restrict__ wv1f, unsigned short* __restrict__ wv2f,
    unsigned short* __restrict__ w1f, unsigned short* __restrict__ w2f,
    unsigned short* __restrict__ w3f)
{
  int bid = blockIdx.x;
  const float* src; unsigned short* dst; int nk, f;
  if (bid < 40)       { src = Wv1; dst = wv1f; nk = 10; f = bid; }
  else if (bid < 80)  { src = Wv2; dst = wv2f; nk = 10; f = bid - 40; }
  else if (bid < 112) { src = W1;  dst = w1f;  nk = 8;  f = bid - 80; }
  else if (bid < 120) { src = W2;  dst = w2f;  nk = 2;  f = bid - 112; }
  else                { src = W3;  dst = w3f;  nk = 2;  f = bid - 120; }
  int nt = f / nk;
  int ks = f - nt*nk;
  int lane = threadIdx.x;
  unsigned short us[8];
  #pragma unroll
  for (int j = 0; j < 8; j++) {
    float v = src[(ks*32 + (lane>>4)*8 + j)*64 + nt*16 + (lane & 15)];
    us[j] = f2bf(v);
  }
  uint4 pk;
  pk.x = (unsigned)us[0] | ((unsigned)us[1] << 16);
  pk.y = (unsigned)us[2] | ((unsigned)us[3] << 16);
  pk.z = (unsigned)us[4] | ((unsigned)us[5] << 16);
  pk.w = (unsigned)us[6] | ((unsigned)us[7] << 16);
  *(uint4*)(dst + ((size_t)f*64 + lane)*8) = pk;
}

// ---------------- graph bucketing ----------------
__global__ void k_hist(const int* __restrict__ senders, int* __restrict__ counts) {
  int i = blockIdx.x * blockDim.x + threadIdx.x;
  if (i < EDGES) atomicAdd(&counts[senders[i]], 1);
}

__global__ void k_scan(const int* __restrict__ counts, int* __restrict__ offsets, int* __restrict__ cursor) {
  __shared__ int sh[1024];
  int t = threadIdx.x;
  int c = counts[t];
  sh[t] = c; __syncthreads();
  for (int d = 1; d < 1024; d <<= 1) {
    int v = (t >= d) ? sh[t-d] : 0;
    __syncthreads();
    sh[t] += v;
    __syncthreads();
  }
  int incl = sh[t];
  int excl = incl - c;
  offsets[t] = excl;
  cursor[t] = excl;
  if (t == 1023) offsets[1024] = incl;
}

__global__ void k_scatter(const int* __restrict__ senders, int* __restrict__ cursor, int* __restrict__ elist) {
  int i = blockIdx.x * blockDim.x + threadIdx.x;
  if (i < EDGES) {
    int pos = atomicAdd(&cursor[senders[i]], 1);
    elist[pos] = i;
  }
}

// ---------------- w = x @ W_w / 8 ----------------
__global__ __launch_bounds__(256) void k_edge_w(
    const float* __restrict__ x, const float* __restrict__ Ww,
    float* __restrict__ w_ws, int E)
{
  const int wid = threadIdx.x >> 6, lane = threadIdx.x & 63;
  const int e = blockIdx.x * 4 + wid;
  if (e >= E) return;
  float xv = x[e*64 + lane];
  float w = 0.f;
  #pragma unroll
  for (int f = 0; f < 64; f++)
    w = fmaf(__shfl(xv, f), Ww[f*64 + lane], w);
  w_ws[e*64 + lane] = w * 0.125f;
}

// ---------------- node aggregation (one wave per node) ----------------
__global__ __launch_bounds__(256) void k_node(
    const float* __restrict__ vec, const float* __restrict__ w_ws,
    const int* __restrict__ offsets, const int* __restrict__ elist,
    float* __restrict__ node_agg)
{
  const int wid = threadIdx.x >> 6, lane = threadIdx.x & 63;
  const int s = blockIdx.x * 4 + wid;
  const int beg = offsets[s], end = offsets[s+1];

  const float S3 = 1.7320508075688772f, S5 = 2.23606797749979f, S15 = 3.872983346207417f;
  const float C33 = 2.091650066335189f, C32 = 5.123475382979799f, C31 = 1.6201851746019651f;
  const float C30 = 1.3228756555322954f, CX = 10.246950765959598f;

  float A[16];
  #pragma unroll
  for (int k = 0; k < 16; k++) A[k] = 0.f;

  for (int ii = beg; ii < end; ii++) {
    int e = elist[ii];
    float vx = vec[e*3+0], vy = vec[e*3+1], vz = vec[e*3+2];
    float d = sqrtf(vx*vx + vy*vy + vz*vz);
    float X = vx/d, Yv = vy/d, Z = vz/d;
    float y[16];
    y[0] = 1.f;
    y[1] = S3*X;  y[2] = S3*Yv;  y[3] = S3*Z;
    y[4] = S15*X*Yv; y[5] = S15*Yv*Z; y[6] = 0.5f*S5*(3.f*Z*Z - 1.f);
    y[7] = S15*X*Z;  y[8] = 0.5f*S15*(X*X - Yv*Yv);
    y[9]  = C33*Yv*(3.f*X*X - Yv*Yv);
    y[10] = CX*X*Yv*Z;
    y[11] = C31*Yv*(5.f*Z*Z - 1.f);
    y[12] = C30*Z*(5.f*Z*Z - 3.f);
    y[13] = C31*X*(5.f*Z*Z - 1.f);
    y[14] = C32*Z*(X*X - Yv*Yv);
    y[15] = C33*X*(X*X - 3.f*Yv*Yv);
    float wv = w_ws[e*64 + lane];
    #pragma unroll
    for (int k = 0; k < 16; k++) A[k] = fmaf(wv, y[k], A[k]);
  }
  float* dst = node_agg + s*1024 + lane;
  #pragma unroll
  for (int k = 0; k < 16; k++) dst[k*64] = A[k];
}

// ---------------- TP helper (fully unrolled; cg reads are wave-uniform -> s_load) ----------------
template<int L1, int L2, int L3>
__device__ __forceinline__ void tp_path(const float* __restrict__ cgp,
    const float a[16], const float b[9], float o[2*L3+1])
{
  constexpr int N1 = 2*L1+1, N2 = 2*L2+1, N3 = 2*L3+1;
  constexpr int AO = (L1==0) ? 0 : (L1==1) ? 1 : (L1==2) ? 4 : 9;
  constexpr int BO = (L2==0) ? 0 : (L2==1) ? 1 : 4;
  #pragma unroll
  for (int k = 0; k < N3; k++) o[k] = 0.f;
  int ci = 0;
  #pragma unroll
  for (int i = 0; i < N1; i++) {
    #pragma unroll
    for (int j = 0; j < N2; j++) {
      float ab = a[AO+i] * b[BO+j];
      #pragma unroll
      for (int k = 0; k < N3; k++) { o[k] = fmaf(ab, cgp[ci], o[k]); ci++; }
    }
  }
}

// ---------------- main fused kernel: TP -> MFMA GEMMs -> outputs ----------------
// EB=4 edges/block, one edge per wave. LDS ~34.3KB -> 4 blocks/CU.
__global__ __launch_bounds__(256, 4) void edge_main(
    const float* __restrict__ vec, const float* __restrict__ x,
    const float* __restrict__ V, const int* __restrict__ senders,
    const float* __restrict__ node_agg, const float* __restrict__ cg,
    const unsigned short* __restrict__ wv1f, const unsigned short* __restrict__ wv2f,
    const unsigned short* __restrict__ w1f, const unsigned short* __restrict__ w2f,
    const unsigned short* __restrict__ w3f,
    float* __restrict__ out, int E, const float* __restrict__ actc)
{
  __shared__ __align__(16) unsigned short V1sh[12*328];  // rows (eloc*3+i), K=320
  __shared__ __align__(16) unsigned short V2sh[20*328];  // rows (eloc*5+i), K=320
  __shared__ __align__(16) unsigned short zrow[336];     // zero row for M-tile padding
  __shared__ __align__(16) unsigned short hsh[4*264];    // rows=edges, K=256 = [x(64)|scal(192)]
  __shared__ __align__(16) unsigned short h1sh[4*72];
  __shared__ __align__(16) unsigned short h2sh[4*72];
  __shared__ __align__(16) float vosh[4*584];            // staged V_out, 576 floats/edge
  __shared__ float ush[EB];

  const int t = threadIdx.x;
  const int wid = t >> 6, lane = t & 63;
  const int e0 = blockIdx.x * EB;
  const size_t E64 = (size_t)E * 64;
  const float inv_actc = *actc;

  if (t < 168) ((unsigned int*)zrow)[t] = 0u;

  // x -> hsh[:, 0:64]
  { int el = t >> 6, o = t & 63;
    hsh[el*264 + o] = f2bf(x[(e0+el)*64 + o]); }

  // ---- TP phase: one edge per wave ----
  {
    const int eloc = wid;
    const int eg = e0 + eloc;
    const int s = senders[eg];

    float a[16];
    const float* nap = node_agg + s*1024 + lane;
    #pragma unroll
    for (int k = 0; k < 16; k++) a[k] = nap[k*64] * 0.25f;

    // V[e][n=lane][j] : 9 contiguous dwords per lane
    float b[9];
    const float* vp = V + (size_t)eg*576 + lane*9;
    #pragma unroll
    for (int j = 0; j < 9; j++) b[j] = vp[j];

    float o1[1], o3[3], o5[5];
    // scal paths -> hsh cols 64 + lane*3 + p
    tp_path<0,0,0>(cg + 0,  a, b, o1); hsh[eloc*264 + 64 + lane*3 + 0] = f2bf(o1[0]);
    tp_path<1,1,0>(cg + 1,  a, b, o1); hsh[eloc*264 + 64 + lane*3 + 1] = f2bf(o1[0]);
    tp_path<2,2,0>(cg + 10, a, b, o1); hsh[eloc*264 + 64 + lane*3 + 2] = f2bf(o1[0]);
    // V1 paths (K index = pb*64 + lane)
    tp_path<0,1,1>(cg + 35, a, b, o3);
    { int r = eloc*3; for (int i=0;i<3;i++) V1sh[(r+i)*328 + 0*64 + lane] = f2bf(o3[i]); }
    tp_path<1,0,1>(cg + 44, a, b, o3);
    { int r = eloc*3; for (int i=0;i<3;i++) V1sh[(r+i)*328 + 1*64 + lane] = f2bf(o3[i]); }
    tp_path<1,2,1>(cg + 53, a, b, o3);
    { int r = eloc*3; for (int i=0;i<3;i++) V1sh[(r+i)*328 + 2*64 + lane] = f2bf(o3[i]); }
    tp_path<2,1,1>(cg + 98, a, b, o3);
    { int r = eloc*3; for (int i=0;i<3;i++) V1sh[(r+i)*328 + 3*64 + lane] = f2bf(o3[i]); }
    tp_path<3,2,1>(cg + 143, a, b, o3);
    { int r = eloc*3; for (int i=0;i<3;i++) V1sh[(r+i)*328 + 4*64 + lane] = f2bf(o3[i]); }
    // V2 paths
    tp_path<0,2,2>(cg + 248, a, b, o5);
    { int r = eloc*5; for (int i=0;i<5;i++) V2sh[(r+i)*328 + 0*64 + lane] = f2bf(o5[i]); }
    tp_path<1,1,2>(cg + 273, a, b, o5);
    { int r = eloc*5; for (int i=0;i<5;i++) V2sh[(r+i)*328 + 1*64 + lane] = f2bf(o5[i]); }
    tp_path<2,0,2>(cg + 318, a, b, o5);
    { int r = eloc*5; for (int i=0;i<5;i++) V2sh[(r+i)*328 + 2*64 + lane] = f2bf(o5[i]); }
    tp_path<2,2,2>(cg + 343, a, b, o5);
    { int r = eloc*5; for (int i=0;i<5;i++) V2sh[(r+i)*328 + 3*64 + lane] = f2bf(o5[i]); }
    tp_path<3,1,2>(cg + 468, a, b, o5);
    { int r = eloc*5; for (int i=0;i<5;i++) V2sh[(r+i)*328 + 4*64 + lane] = f2bf(o5[i]); }

    if (lane == 0) {
      float vx = vec[eg*3+0], vy = vec[eg*3+1], vz = vec[eg*3+2];
      float d = sqrtf(vx*vx + vy*vy + vz*vz);
      float u = 0.f;
      if (d < 1.f) {
        float d3 = d*d*d, d6 = d3*d3, d7 = d6*d, d8 = d7*d;
        u = 1.f - 28.f*d6 + 48.f*d7 - 21.f*d8;
      }
      ush[eloc] = u;
    }
  }
  __syncthreads();

  // ---- MFMA GEMM phase: wave wid owns output-column tile ntile=wid (16 cols) ----
  const int ntile = wid;
  const int qr = lane >> 4;
  const int ml = lane & 15;
  const float s320 = 0.05590169943749474f;  // 1/sqrt(320)

  // V1: M=12 (1 tile), K=320 -> vosh
  {
    f32x4 acc = (f32x4){0,0,0,0};
    const unsigned short* p0 = (ml < 12) ? &V1sh[ml*328] : zrow;
    const unsigned short* bb = wv1f + ((size_t)(ntile*10)*64 + lane)*8;
    #pragma unroll
    for (int ks = 0; ks < 10; ks++) {
      short8 bf = *(const short8*)(bb + ks*512);
      short8 af = *(const short8*)(p0 + ks*32 + qr*8);
      acc = __builtin_amdgcn_mfma_f32_16x16x32_bf16(af, bf, acc, 0, 0, 0);
    }
    #pragma unroll
    for (int r = 0; r < 4; r++) {
      int row = qr*4 + r;
      if (row < 12) {
        int el = row / 3, i = row - (row/3)*3;
        vosh[el*584 + (ntile*16+ml)*9 + 1 + i] = acc[r] * s320;
      }
    }
  }

  // V2: M=20 (2 tiles), K=320 -> vosh
  {
    f32x4 acc[2]; acc[0] = (f32x4){0,0,0,0}; acc[1] = (f32x4){0,0,0,0};
    const unsigned short* p0 = &V2sh[ml*328];
    const unsigned short* p1 = (16+ml < 20) ? &V2sh[(16+ml)*328] : zrow;
    const unsigned short* bb = wv2f + ((size_t)(ntile*10)*64 + lane)*8;
    #pragma unroll
    for (int ks = 0; ks < 10; ks++) {
      short8 bf = *(const short8*)(bb + ks*512);
      int ao = ks*32 + qr*8;
      short8 af0 = *(const short8*)(p0 + ao);
      short8 af1 = *(const short8*)(p1 + ao);
      acc[0] = __builtin_amdgcn_mfma_f32_16x16x32_bf16(af0, bf, acc[0], 0, 0, 0);
      acc[1] = __builtin_amdgcn_mfma_f32_16x16x32_bf16(af1, bf, acc[1], 0, 0, 0);
    }
    #pragma unroll
    for (int mt = 0; mt < 2; mt++) {
      #pragma unroll
      for (int r = 0; r < 4; r++) {
        int row = mt*16 + qr*4 + r;
        if (row < 20) {
          int el = row / 5, i = row - (row/5)*5;
          vosh[el*584 + (ntile*16+ml)*9 + 4 + i] = acc[mt][r] * s320;
        }
      }
    }
  }

  // V_out channel 0 = 0
  { int el = t >> 6, o = t & 63;
    vosh[el*584 + o*9] = 0.f; }

  // ---- MLP via MFMA (M=4 real rows padded to 16) ----
  const unsigned short* hp = (ml < 4) ? &hsh[ml*264] : zrow;
  {
    f32x4 c = (f32x4){0,0,0,0};
    const unsigned short* bb = w1f + ((size_t)(ntile*8)*64 + lane)*8;
    #pragma unroll
    for (int ks = 0; ks < 8; ks++) {
      short8 bf = *(const short8*)(bb + ks*512);
      short8 af = *(const short8*)(hp + ks*32 + qr*8);
      c = __builtin_amdgcn_mfma_f32_16x16x32_bf16(af, bf, c, 0, 0, 0);
    }
    #pragma unroll
    for (int r = 0; r < 4; r++) {
      int row = qr*4 + r;
      if (row < 4) {
        float v = c[r] * 0.0625f;
        float sv = v / (1.f + expf(-v)) * inv_actc;
        h1sh[row*72 + ntile*16 + ml] = f2bf(sv);
      }
    }
  }
  __syncthreads();
  {
    f32x4 c = (f32x4){0,0,0,0};
    const unsigned short* ap = (ml < 4) ? &h1sh[ml*72] : zrow;
    const unsigned short* bb = w2f + ((size_t)(ntile*2)*64 + lane)*8;
    #pragma unroll
    for (int ks = 0; ks < 2; ks++) {
      short8 bf = *(const short8*)(bb + ks*512);
      short8 af = *(const short8*)(ap + ks*32 + qr*8);
      c = __builtin_amdgcn_mfma_f32_16x16x32_bf16(af, bf, c, 0, 0, 0);
    }
    #pragma unroll
    for (int r = 0; r < 4; r++) {
      int row = qr*4 + r;
      if (row < 4) {
        float v = c[r] * 0.125f;
        float sv = v / (1.f + expf(-v)) * inv_actc;
        h2sh[row*72 + ntile*16 + ml] = f2bf(sv);
      }
    }
  }
  __syncthreads();
  {
    f32x4 c = (f32x4){0,0,0,0};
    const unsigned short* ap = (ml < 4) ? &h2sh[ml*72] : zrow;
    const unsigned short* bb = w3f + ((size_t)(ntile*2)*64 + lane)*8;
    #pragma unroll
    for (int ks = 0; ks < 2; ks++) {
      short8 bf = *(const short8*)(bb + ks*512);
      short8 af = *(const short8*)(ap + ks*32 + qr*8);
      c = __builtin_amdgcn_mfma_f32_16x16x32_bf16(af, bf, c, 0, 0, 0);
    }
    #pragma unroll
    for (int r = 0; r < 4; r++) {
      int row = qr*4 + r;
      if (row < 4) {
        float v = c[r] * 0.125f;
        out[(size_t)(e0+row)*64 + ntile*16 + ml] = ush[row] * v;
      }
    }
  }

  // vosh complete since before first MLP sync; coalesced float4 store of V_out
  for (int q = t; q < 576; q += 256) {
    int el = q / 144, i4 = q - (q/144)*144;
    ((f32x4*)(out + E64 + (size_t)(e0+el)*576))[i4] = ((f32x4*)(vosh + el*584))[i4];
  }
}

extern "C" void kernel_launch(void* const* d_in, const int* in_sizes, int n_in,
                              void* d_out, int out_size, void* d_ws, size_t ws_size,
                              hipStream_t stream)
{
  const float* vec     = (const float*)d_in[0];
  const float* x       = (const float*)d_in[1];
  const float* V       = (const float*)d_in[2];
  const int*   senders = (const int*)  d_in[3];
  const float* Ww      = (const float*)d_in[4];
  const float* W1      = (const float*)d_in[5];
  const float* W2      = (const float*)d_in[6];
  const float* W3      = (const float*)d_in[7];
  const float* Wv1     = (const float*)d_in[8];
  const float* Wv2     = (const float*)d_in[9];
  float* out = (float*)d_out;
  const int E = in_sizes[0] / 3;

  // ---- workspace layout ----
  char* base = (char*)d_ws;
  float* node_agg = (float*)(base);                      // 4 MB
  float* w_ws     = (float*)(base + (4<<20));            // 4 MB
  float* cg       = (float*)(base + (8<<20));            // 573 floats
  float* actc     = (float*)(base + (8<<20) + 2400);     // 1 float
  double* actp    = (double*)(base + (8<<20) + 2432);    // 128 doubles
  int* counts     = (int*)  (base + (8<<20) + 4096);     // 4 KB
  int* offsets    = (int*)  (base + (8<<20) + 8192);     // 1025 ints
  int* cursor     = (int*)  (base + (8<<20) + 16384);    // 4 KB
  int* elist      = (int*)  (base + (8<<20) + 20480);    // 64 KB
  unsigned short* wv1f = (unsigned short*)(base + (8<<20) + 86016);   // 40 KB
  unsigned short* wv2f = (unsigned short*)(base + (8<<20) + 126976);  // 40 KB
  unsigned short* w1f  = (unsigned short*)(base + (8<<20) + 167936);  // 32 KB
  unsigned short* w2f  = (unsigned short*)(base + (8<<20) + 200704);  // 8 KB
  unsigned short* w3f  = (unsigned short*)(base + (8<<20) + 208896);  // 8 KB

  cg_setup<<<13, 128, 0, stream>>>(cg);
  act1<<<128, 256, 0, stream>>>(actp, counts);
  act2<<<1, 128, 0, stream>>>(actp, actc);
  conv_all<<<128, 64, 0, stream>>>(Wv1, Wv2, W1, W2, W3, wv1f, wv2f, w1f, w2f, w3f);
  k_edge_w<<<(E+3)/4, 256, 0, stream>>>(x, Ww, w_ws, E);
  k_hist<<<E/256, 256, 0, stream>>>(senders, counts);
  k_scan<<<1, 1024, 0, stream>>>(counts, offsets, cursor);
  k_scatter<<<E/256, 256, 0, stream>>>(senders, cursor, elist);
  k_node<<<NNODES/4, 256, 0, stream>>>(vec, w_ws, offsets, elist, node_agg);
  edge_main<<<E/EB, 256, 0, stream>>>(vec, x, V, senders, node_agg, cg,
                                      wv1f, wv2f, w1f, w2f, w3f, out, E, actc);
}

// Round 5
// 185.647 us; speedup vs baseline: 7.8136x; 1.1056x over previous
//
#include <hip/hip_runtime.h>
#include <math.h>

#define NNODES 1024
#define EDGES 16384
#define EB 4   // edges per block in edge_main (one edge per wave)

typedef __attribute__((ext_vector_type(8))) short short8;
typedef __attribute__((ext_vector_type(4))) float f32x4;

__device__ __forceinline__ unsigned short f2bf(float f) {
  union { float f; unsigned int u; } v; v.f = f;
  unsigned int r = v.u + 0x7fffu + ((v.u >> 16) & 1u);
  return (unsigned short)(r >> 16);
}

// ---------------- path tables ----------------
__device__ __constant__ int PL1[13] = {0,1,2, 0,1,1,2,3, 0,1,2,2,3};
__device__ __constant__ int PL2[13] = {0,1,2, 1,0,2,1,2, 2,1,0,2,1};
__device__ __constant__ int PL3[13] = {0,0,0, 1,1,1,1,1, 2,2,2,2,2};
__device__ __constant__ int PCG[13] = {0,1,10, 35,44,53,98,143, 248,273,318,343,468};

// ---------------- SH polynomial tables for CG setup ----------------
__device__ __constant__ signed char SH_NT[16] = {1, 1,1,1, 1,1,2,1,2, 2,1,2,2,2,2,2};
__device__ __constant__ signed char SH_CID[16][2] = {
  {0,0},{1,0},{1,0},{1,0},
  {2,0},{2,0},{3,4},{2,0},{5,6},
  {7,8},{9,0},{10,11},{12,13},{10,11},{14,15},{16,17}};
__device__ __constant__ signed char SH_EXP[16][2][3] = {
  {{0,0,0},{0,0,0}},
  {{1,0,0},{0,0,0}}, {{0,1,0},{0,0,0}}, {{0,0,1},{0,0,0}},
  {{1,1,0},{0,0,0}}, {{0,1,1},{0,0,0}}, {{0,0,2},{0,0,0}}, {{1,0,1},{0,0,0}}, {{2,0,0},{0,2,0}},
  {{2,1,0},{0,3,0}}, {{1,1,1},{0,0,0}}, {{0,1,2},{0,1,0}}, {{0,0,3},{0,0,1}},
  {{1,0,2},{1,0,0}}, {{2,0,1},{0,2,1}}, {{3,0,0},{1,2,0}}};

__device__ double dfact_d(int n) { double r = 1.0; while (n > 1) { r *= n; n -= 2; } return r; }

// ---------------- prep: CG (b0-12) + ACT partials (b13-20) + weight pack (b21-52) ----
// blocks 0..3 also zero the per-node counters.
__global__ __launch_bounds__(256) void prep(
    const float* __restrict__ Wv1, const float* __restrict__ Wv2,
    const float* __restrict__ W1, const float* __restrict__ W2, const float* __restrict__ W3,
    unsigned short* __restrict__ wv1f, unsigned short* __restrict__ wv2f,
    unsigned short* __restrict__ w1f, unsigned short* __restrict__ w2f,
    unsigned short* __restrict__ w3f,
    float* __restrict__ cg, float* __restrict__ actp, int* __restrict__ counts)
{
  const int bid = blockIdx.x;
  const int t = threadIdx.x;

  if (bid < 13) {
    if (bid < 4) counts[bid*256 + t] = 0;
    // ---- CG tensor for path bid (double, exact replica of reference) ----
    __shared__ double sh[256];
    const int p = bid;
    double S3 = sqrt(3.0), S5 = sqrt(5.0), S15 = sqrt(15.0);
    double C33 = sqrt(70.0)/4.0, C32 = sqrt(105.0)/2.0, C31 = sqrt(42.0)/4.0;
    double C30 = sqrt(7.0)/2.0,  CX  = sqrt(105.0);
    double CV[18] = {1.0, S3, S15, 1.5*S5, -0.5*S5, 0.5*S15, -0.5*S15,
                     3.0*C33, -C33, CX, 5.0*C31, -C31, 5.0*C30, -3.0*C30,
                     C32, -C32, C33, -3.0*C33};
    const int LOFF[4] = {0,1,4,9};
    int l1 = PL1[p], l2 = PL2[p], l3 = PL3[p];
    int n1 = 2*l1+1, n2 = 2*l2+1, n3 = 2*l3+1;
    int nent = n1*n2*n3;
    double v = 0.0;
    if (t < nent) {
      int i = t / (n2*n3);
      int rem = t - i*(n2*n3);
      int j = rem / n3;
      int k = rem - j*n3;
      int lm1 = LOFF[l1]+i, lm2 = LOFF[l2]+j, lm3 = LOFF[l3]+k;
      for (int t1 = 0; t1 < SH_NT[lm1]; t1++)
      for (int t2 = 0; t2 < SH_NT[lm2]; t2++)
      for (int t3 = 0; t3 < SH_NT[lm3]; t3++) {
        int a = SH_EXP[lm1][t1][0] + SH_EXP[lm2][t2][0] + SH_EXP[lm3][t3][0];
        int b = SH_EXP[lm1][t1][1] + SH_EXP[lm2][t2][1] + SH_EXP[lm3][t3][1];
        int c = SH_EXP[lm1][t1][2] + SH_EXP[lm2][t2][2] + SH_EXP[lm3][t3][2];
        if ((a & 1) | (b & 1) | (c & 1)) continue;
        double mi = dfact_d(a-1) * dfact_d(b-1) * dfact_d(c-1) / dfact_d(a+b+c+1);
        v += CV[SH_CID[lm1][t1]] * CV[SH_CID[lm2][t2]] * CV[SH_CID[lm3][t3]] * mi;
      }
    }
    sh[t] = (t < nent) ? v*v : 0.0;
    __syncthreads();
    for (int d = 128; d > 0; d >>= 1) {
      if (t < d) sh[t] += sh[t+d];
      __syncthreads();
    }
    double scale = sqrt((double)(2*l3+1)) / sqrt(sh[0]);
    if (t < nent) cg[PCG[p] + t] = (float)(v * scale);

  } else if (bid < 21) {
    // ---- ACT_C partial sums (float; 8 blocks x 256 threads over 200001 pts) ----
    __shared__ float shf[256];
    const int b = bid - 13;
    const float dz = 24.0f / 200000.0f;
    float s = 0.f;
    for (int i = b*256 + t; i <= 200000; i += 8*256) {
      float z = -12.0f + dz * (float)i;
      float ph = __expf(-0.5f * z * z) * 0.3989422804014327f;
      float sl = z / (1.f + __expf(-z));
      s = fmaf(sl*sl, ph, s);
    }
    shf[t] = s;
    __syncthreads();
    for (int d = 128; d > 0; d >>= 1) {
      if (t < d) shf[t] += shf[t + d];
      __syncthreads();
    }
    if (t == 0) actp[b] = shf[0];

  } else {
    // ---- weight fragment pack: 4 fragments per block ----
    // frag g: element j of lane l = W[ks*32 + (l>>4)*8 + j][nt*16 + (l&15)]
    const int wid = t >> 6, lane = t & 63;
    const int g = (bid - 21)*4 + wid;
    const float* src; unsigned short* dst; int nk, f;
    if (g < 40)       { src = Wv1; dst = wv1f; nk = 10; f = g; }
    else if (g < 80)  { src = Wv2; dst = wv2f; nk = 10; f = g - 40; }
    else if (g < 112) { src = W1;  dst = w1f;  nk = 8;  f = g - 80; }
    else if (g < 120) { src = W2;  dst = w2f;  nk = 2;  f = g - 112; }
    else              { src = W3;  dst = w3f;  nk = 2;  f = g - 120; }
    int nt = f / nk;
    int ks = f - nt*nk;
    unsigned short us[8];
    #pragma unroll
    for (int j = 0; j < 8; j++) {
      float v = src[(ks*32 + (lane>>4)*8 + j)*64 + nt*16 + (lane & 15)];
      us[j] = f2bf(v);
    }
    uint4 pk;
    pk.x = (unsigned)us[0] | ((unsigned)us[1] << 16);
    pk.y = (unsigned)us[2] | ((unsigned)us[3] << 16);
    pk.z = (unsigned)us[4] | ((unsigned)us[5] << 16);
    pk.w = (unsigned)us[6] | ((unsigned)us[7] << 16);
    *(uint4*)(dst + ((size_t)f*64 + lane)*8) = pk;
  }
}

// ---------------- edgepass: w = x @ W_w / 8, plus bucket scatter ----------------
__global__ __launch_bounds__(256) void edgepass(
    const float* __restrict__ x, const float* __restrict__ Ww,
    const int* __restrict__ senders,
    float* __restrict__ w_ws, int* __restrict__ counts, int* __restrict__ elist, int E)
{
  const int wid = threadIdx.x >> 6, lane = threadIdx.x & 63;
  const int e = blockIdx.x * 4 + wid;
  if (e >= E) return;
  float xv = x[e*64 + lane];
  float w = 0.f;
  #pragma unroll
  for (int f = 0; f < 64; f++)
    w = fmaf(__shfl(xv, f), Ww[f*64 + lane], w);
  w_ws[e*64 + lane] = w * 0.125f;
  if (lane == 0) {
    int s = senders[e];
    int pos = atomicAdd(&counts[s], 1) & 63;  // P(deg>=64) ~ 1e-18 for Poisson(16)
    elist[s*64 + pos] = e;
  }
}

// ---------------- node aggregation (one wave per node) ----------------
// node_agg layout: [node][n(64)][k(16)] -> contiguous 16 floats per lane
__global__ __launch_bounds__(256) void k_node(
    const float* __restrict__ vec, const float* __restrict__ w_ws,
    const int* __restrict__ counts, const int* __restrict__ elist,
    float* __restrict__ node_agg)
{
  const int wid = threadIdx.x >> 6, lane = threadIdx.x & 63;
  const int s = blockIdx.x * 4 + wid;
  const int deg = min(counts[s], 64);

  const float S3 = 1.7320508075688772f, S5 = 2.23606797749979f, S15 = 3.872983346207417f;
  const float C33 = 2.091650066335189f, C32 = 5.123475382979799f, C31 = 1.6201851746019651f;
  const float C30 = 1.3228756555322954f, CX = 10.246950765959598f;

  float A[16];
  #pragma unroll
  for (int k = 0; k < 16; k++) A[k] = 0.f;

  for (int ii = 0; ii < deg; ii++) {
    int e = elist[s*64 + ii];
    float vx = vec[e*3+0], vy = vec[e*3+1], vz = vec[e*3+2];
    float d = sqrtf(vx*vx + vy*vy + vz*vz);
    float X = vx/d, Yv = vy/d, Z = vz/d;
    float y[16];
    y[0] = 1.f;
    y[1] = S3*X;  y[2] = S3*Yv;  y[3] = S3*Z;
    y[4] = S15*X*Yv; y[5] = S15*Yv*Z; y[6] = 0.5f*S5*(3.f*Z*Z - 1.f);
    y[7] = S15*X*Z;  y[8] = 0.5f*S15*(X*X - Yv*Yv);
    y[9]  = C33*Yv*(3.f*X*X - Yv*Yv);
    y[10] = CX*X*Yv*Z;
    y[11] = C31*Yv*(5.f*Z*Z - 1.f);
    y[12] = C30*Z*(5.f*Z*Z - 3.f);
    y[13] = C31*X*(5.f*Z*Z - 1.f);
    y[14] = C32*Z*(X*X - Yv*Yv);
    y[15] = C33*X*(X*X - 3.f*Yv*Yv);
    float wv = w_ws[e*64 + lane];
    #pragma unroll
    for (int k = 0; k < 16; k++) A[k] = fmaf(wv, y[k], A[k]);
  }
  float* dst = node_agg + s*1024 + lane*16;
  #pragma unroll
  for (int k = 0; k < 4; k++)
    ((f32x4*)dst)[k] = (f32x4){A[4*k], A[4*k+1], A[4*k+2], A[4*k+3]};
}

// ---------------- TP helper (fully unrolled; cg reads are wave-uniform -> s_load) ----------------
template<int L1, int L2, int L3>
__device__ __forceinline__ void tp_path(const float* __restrict__ cgp,
    const float a[16], const float b[9], float o[2*L3+1])
{
  constexpr int N1 = 2*L1+1, N2 = 2*L2+1, N3 = 2*L3+1;
  constexpr int AO = (L1==0) ? 0 : (L1==1) ? 1 : (L1==2) ? 4 : 9;
  constexpr int BO = (L2==0) ? 0 : (L2==1) ? 1 : 4;
  #pragma unroll
  for (int k = 0; k < N3; k++) o[k] = 0.f;
  int ci = 0;
  #pragma unroll
  for (int i = 0; i < N1; i++) {
    #pragma unroll
    for (int j = 0; j < N2; j++) {
      float ab = a[AO+i] * b[BO+j];
      #pragma unroll
      for (int k = 0; k < N3; k++) { o[k] = fmaf(ab, cgp[ci], o[k]); ci++; }
    }
  }
}

// ---------------- main fused kernel: TP -> MFMA GEMMs -> outputs ----------------
// EB=4 edges/block, one edge per wave. LDS ~34.3KB -> 4 blocks/CU.
__global__ __launch_bounds__(256, 4) void edge_main(
    const float* __restrict__ vec, const float* __restrict__ x,
    const float* __restrict__ V, const int* __restrict__ senders,
    const float* __restrict__ node_agg, const float* __restrict__ cg,
    const unsigned short* __restrict__ wv1f, const unsigned short* __restrict__ wv2f,
    const unsigned short* __restrict__ w1f, const unsigned short* __restrict__ w2f,
    const unsigned short* __restrict__ w3f,
    float* __restrict__ out, int E, const float* __restrict__ actp)
{
  __shared__ __align__(16) unsigned short V1sh[12*328];  // rows (eloc*3+i), K=320
  __shared__ __align__(16) unsigned short V2sh[20*328];  // rows (eloc*5+i), K=320
  __shared__ __align__(16) unsigned short zrow[336];     // zero row for M-tile padding
  __shared__ __align__(16) unsigned short hsh[4*264];    // rows=edges, K=256 = [x(64)|scal(192)]
  __shared__ __align__(16) unsigned short h1sh[4*72];
  __shared__ __align__(16) unsigned short h2sh[4*72];
  __shared__ __align__(16) float vosh[4*584];            // staged V_out, 576 floats/edge
  __shared__ float ush[EB];

  const int t = threadIdx.x;
  const int wid = t >> 6, lane = t & 63;
  const int e0 = blockIdx.x * EB;
  const size_t E64 = (size_t)E * 64;
  const float inv_actc = 1.f / sqrtf((actp[0]+actp[1]+actp[2]+actp[3]
                                     +actp[4]+actp[5]+actp[6]+actp[7]) * (24.0f/200000.0f));

  if (t < 168) ((unsigned int*)zrow)[t] = 0u;

  // x -> hsh[:, 0:64]
  { int el = t >> 6, o = t & 63;
    hsh[el*264 + o] = f2bf(x[(e0+el)*64 + o]); }

  // ---- TP phase: one edge per wave ----
  {
    const int eloc = wid;
    const int eg = e0 + eloc;
    const int s = senders[eg];

    float a[16];
    const float* nap = node_agg + s*1024 + lane*16;
    #pragma unroll
    for (int k = 0; k < 16; k++) a[k] = nap[k] * 0.25f;

    // V[e][n=lane][j] : 9 contiguous dwords per lane
    float b[9];
    const float* vp = V + (size_t)eg*576 + lane*9;
    #pragma unroll
    for (int j = 0; j < 9; j++) b[j] = vp[j];

    float o1[1], o3[3], o5[5];
    // scal paths -> hsh cols 64 + lane*3 + p
    tp_path<0,0,0>(cg + 0,  a, b, o1); hsh[eloc*264 + 64 + lane*3 + 0] = f2bf(o1[0]);
    tp_path<1,1,0>(cg + 1,  a, b, o1); hsh[eloc*264 + 64 + lane*3 + 1] = f2bf(o1[0]);
    tp_path<2,2,0>(cg + 10, a, b, o1); hsh[eloc*264 + 64 + lane*3 + 2] = f2bf(o1[0]);
    // V1 paths (K index = pb*64 + lane)
    tp_path<0,1,1>(cg + 35, a, b, o3);
    { int r = eloc*3; for (int i=0;i<3;i++) V1sh[(r+i)*328 + 0*64 + lane] = f2bf(o3[i]); }
    tp_path<1,0,1>(cg + 44, a, b, o3);
    { int r = eloc*3; for (int i=0;i<3;i++) V1sh[(r+i)*328 + 1*64 + lane] = f2bf(o3[i]); }
    tp_path<1,2,1>(cg + 53, a, b, o3);
    { int r = eloc*3; for (int i=0;i<3;i++) V1sh[(r+i)*328 + 2*64 + lane] = f2bf(o3[i]); }
    tp_path<2,1,1>(cg + 98, a, b, o3);
    { int r = eloc*3; for (int i=0;i<3;i++) V1sh[(r+i)*328 + 3*64 + lane] = f2bf(o3[i]); }
    tp_path<3,2,1>(cg + 143, a, b, o3);
    { int r = eloc*3; for (int i=0;i<3;i++) V1sh[(r+i)*328 + 4*64 + lane] = f2bf(o3[i]); }
    // V2 paths
    tp_path<0,2,2>(cg + 248, a, b, o5);
    { int r = eloc*5; for (int i=0;i<5;i++) V2sh[(r+i)*328 + 0*64 + lane] = f2bf(o5[i]); }
    tp_path<1,1,2>(cg + 273, a, b, o5);
    { int r = eloc*5; for (int i=0;i<5;i++) V2sh[(r+i)*328 + 1*64 + lane] = f2bf(o5[i]); }
    tp_path<2,0,2>(cg + 318, a, b, o5);
    { int r = eloc*5; for (int i=0;i<5;i++) V2sh[(r+i)*328 + 2*64 + lane] = f2bf(o5[i]); }
    tp_path<2,2,2>(cg + 343, a, b, o5);
    { int r = eloc*5; for (int i=0;i<5;i++) V2sh[(r+i)*328 + 3*64 + lane] = f2bf(o5[i]); }
    tp_path<3,1,2>(cg + 468, a, b, o5);
    { int r = eloc*5; for (int i=0;i<5;i++) V2sh[(r+i)*328 + 4*64 + lane] = f2bf(o5[i]); }

    if (lane == 0) {
      float vx = vec[eg*3+0], vy = vec[eg*3+1], vz = vec[eg*3+2];
      float d = sqrtf(vx*vx + vy*vy + vz*vz);
      float u = 0.f;
      if (d < 1.f) {
        float d3 = d*d*d, d6 = d3*d3, d7 = d6*d, d8 = d7*d;
        u = 1.f - 28.f*d6 + 48.f*d7 - 21.f*d8;
      }
      ush[eloc] = u;
    }
  }
  __syncthreads();

  // ---- MFMA GEMM phase: wave wid owns output-column tile ntile=wid (16 cols) ----
  const int ntile = wid;
  const int qr = lane >> 4;
  const int ml = lane & 15;
  const float s320 = 0.05590169943749474f;  // 1/sqrt(320)

  // V1: M=12 (1 tile), K=320 -> vosh
  {
    f32x4 acc = (f32x4){0,0,0,0};
    const unsigned short* p0 = (ml < 12) ? &V1sh[ml*328] : zrow;
    const unsigned short* bb = wv1f + ((size_t)(ntile*10)*64 + lane)*8;
    #pragma unroll
    for (int ks = 0; ks < 10; ks++) {
      short8 bf = *(const short8*)(bb + ks*512);
      short8 af = *(const short8*)(p0 + ks*32 + qr*8);
      acc = __builtin_amdgcn_mfma_f32_16x16x32_bf16(af, bf, acc, 0, 0, 0);
    }
    #pragma unroll
    for (int r = 0; r < 4; r++) {
      int row = qr*4 + r;
      if (row < 12) {
        int el = row / 3, i = row - (row/3)*3;
        vosh[el*584 + (ntile*16+ml)*9 + 1 + i] = acc[r] * s320;
      }
    }
  }

  // V2: M=20 (2 tiles), K=320 -> vosh
  {
    f32x4 acc[2]; acc[0] = (f32x4){0,0,0,0}; acc[1] = (f32x4){0,0,0,0};
    const unsigned short* p0 = &V2sh[ml*328];
    const unsigned short* p1 = (16+ml < 20) ? &V2sh[(16+ml)*328] : zrow;
    const unsigned short* bb = wv2f + ((size_t)(ntile*10)*64 + lane)*8;
    #pragma unroll
    for (int ks = 0; ks < 10; ks++) {
      short8 bf = *(const short8*)(bb + ks*512);
      int ao = ks*32 + qr*8;
      short8 af0 = *(const short8*)(p0 + ao);
      short8 af1 = *(const short8*)(p1 + ao);
      acc[0] = __builtin_amdgcn_mfma_f32_16x16x32_bf16(af0, bf, acc[0], 0, 0, 0);
      acc[1] = __builtin_amdgcn_mfma_f32_16x16x32_bf16(af1, bf, acc[1], 0, 0, 0);
    }
    #pragma unroll
    for (int mt = 0; mt < 2; mt++) {
      #pragma unroll
      for (int r = 0; r < 4; r++) {
        int row = mt*16 + qr*4 + r;
        if (row < 20) {
          int el = row / 5, i = row - (row/5)*5;
          vosh[el*584 + (ntile*16+ml)*9 + 4 + i] = acc[mt][r] * s320;
        }
      }
    }
  }

  // V_out channel 0 = 0
  { int el = t >> 6, o = t & 63;
    vosh[el*584 + o*9] = 0.f; }

  // ---- MLP via MFMA (M=4 real rows padded to 16) ----
  const unsigned short* hp = (ml < 4) ? &hsh[ml*264] : zrow;
  {
    f32x4 c = (f32x4){0,0,0,0};
    const unsigned short* bb = w1f + ((size_t)(ntile*8)*64 + lane)*8;
    #pragma unroll
    for (int ks = 0; ks < 8; ks++) {
      short8 bf = *(const short8*)(bb + ks*512);
      short8 af = *(const short8*)(hp + ks*32 + qr*8);
      c = __builtin_amdgcn_mfma_f32_16x16x32_bf16(af, bf, c, 0, 0, 0);
    }
    #pragma unroll
    for (int r = 0; r < 4; r++) {
      int row = qr*4 + r;
      if (row < 4) {
        float v = c[r] * 0.0625f;
        float sv = v / (1.f + expf(-v)) * inv_actc;
        h1sh[row*72 + ntile*16 + ml] = f2bf(sv);
      }
    }
  }
  __syncthreads();
  {
    f32x4 c = (f32x4){0,0,0,0};
    const unsigned short* ap = (ml < 4) ? &h1sh[ml*72] : zrow;
    const unsigned short* bb = w2f + ((size_t)(ntile*2)*64 + lane)*8;
    #pragma unroll
    for (int ks = 0; ks < 2; ks++) {
      short8 bf = *(const short8*)(bb + ks*512);
      short8 af = *(const short8*)(ap + ks*32 + qr*8);
      c = __builtin_amdgcn_mfma_f32_16x16x32_bf16(af, bf, c, 0, 0, 0);
    }
    #pragma unroll
    for (int r = 0; r < 4; r++) {
      int row = qr*4 + r;
      if (row < 4) {
        float v = c[r] * 0.125f;
        float sv = v / (1.f + expf(-v)) * inv_actc;
        h2sh[row*72 + ntile*16 + ml] = f2bf(sv);
      }
    }
  }
  __syncthreads();
  {
    f32x4 c = (f32x4){0,0,0,0};
    const unsigned short* ap = (ml < 4) ? &h2sh[ml*72] : zrow;
    const unsigned short* bb = w3f + ((size_t)(ntile*2)*64 + lane)*8;
    #pragma unroll
    for (int ks = 0; ks < 2; ks++) {
      short8 bf = *(const short8*)(bb + ks*512);
      short8 af = *(const short8*)(ap + ks*32 + qr*8);
      c = __builtin_amdgcn_mfma_f32_16x16x32_bf16(af, bf, c, 0, 0, 0);
    }
    #pragma unroll
    for (int r = 0; r < 4; r++) {
      int row = qr*4 + r;
      if (row < 4) {
        float v = c[r] * 0.125f;
        out[(size_t)(e0+row)*64 + ntile*16 + ml] = ush[row] * v;
      }
    }
  }

  // coalesced float4 store of staged V_out
  for (int q = t; q < 576; q += 256) {
    int el = q / 144, i4 = q - (q/144)*144;
    ((f32x4*)(out + E64 + (size_t)(e0+el)*576))[i4] = ((f32x4*)(vosh + el*584))[i4];
  }
}

extern "C" void kernel_launch(void* const* d_in, const int* in_sizes, int n_in,
                              void* d_out, int out_size, void* d_ws, size_t ws_size,
                              hipStream_t stream)
{
  const float* vec     = (const float*)d_in[0];
  const float* x       = (const float*)d_in[1];
  const float* V       = (const float*)d_in[2];
  const int*   senders = (const int*)  d_in[3];
  const float* Ww      = (const float*)d_in[4];
  const float* W1      = (const float*)d_in[5];
  const float* W2      = (const float*)d_in[6];
  const float* W3      = (const float*)d_in[7];
  const float* Wv1     = (const float*)d_in[8];
  const float* Wv2     = (const float*)d_in[9];
  float* out = (float*)d_out;
  const int E = in_sizes[0] / 3;

  // ---- workspace layout ----
  char* base = (char*)d_ws;
  float* node_agg = (float*)(base);                        // 4 MB  [node][n][k]
  float* w_ws     = (float*)(base + (4<<20));              // 4 MB
  float* cg       = (float*)(base + (8<<20));              // 573 floats
  float* actp     = (float*)(base + (8<<20) + 4096);       // 8 floats
  int* counts     = (int*)  (base + (8<<20) + 8192);       // 1024 ints
  int* elist      = (int*)  (base + (8<<20) + 12288);      // 1024*64 ints = 256 KB
  unsigned short* wv1f = (unsigned short*)(base + (8<<20) + 278528);  // 40 KB
  unsigned short* wv2f = (unsigned short*)(base + (8<<20) + 319488);  // 40 KB
  unsigned short* w1f  = (unsigned short*)(base + (8<<20) + 360448);  // 32 KB
  unsigned short* w2f  = (unsigned short*)(base + (8<<20) + 393216);  // 8 KB
  unsigned short* w3f  = (unsigned short*)(base + (8<<20) + 401408);  // 8 KB

  prep<<<53, 256, 0, stream>>>(Wv1, Wv2, W1, W2, W3,
                               wv1f, wv2f, w1f, w2f, w3f, cg, actp, counts);
  edgepass<<<(E+3)/4, 256, 0, stream>>>(x, Ww, senders, w_ws, counts, elist, E);
  k_node<<<NNODES/4, 256, 0, stream>>>(vec, w_ws, counts, elist, node_agg);
  edge_main<<<E/EB, 256, 0, stream>>>(vec, x, V, senders, node_agg, cg,
                                      wv1f, wv2f, w1f, w2f, w3f, out, E, actp);
}